// Round 5
// baseline (111.863 us; speedup 1.0000x reference)
//
#include <hip/hip_runtime.h>
#include <math.h>

#define B_   1024
#define L_   200
#define DIM_ 100
#define NP   128   // padded N (100 -> 128)
#define K_   1024
#define NCH  8     // split-K chunks per GEMM
#define KCH  (K_ / NCH)   // 128 K-rows per chunk
#define BM   16

// ---------------- Kernel 1: gather + mean-pool (float4 gathers) -------------
// relP[b,d] = (sum_l emb0[items[b,l]][d]) / slen[b]; emb idx 0 = zero row.
// Rows are 400 B = 25 aligned float4. 256 thr = 8 item-streams x 32 f4-cols.
__global__ __launch_bounds__(256) void gather_pool_k(
    const float* __restrict__ emb, const int* __restrict__ items,
    const float* __restrict__ slen, float4* __restrict__ relP4) {
  const int b = blockIdx.x;
  const int t = threadIdx.x;
  const int s = t >> 5;            // item stream 0..7
  const int c = t & 31;            // float4 col, valid c<25
  const int* __restrict__ row = items + b * L_;
  float4 acc = make_float4(0.f, 0.f, 0.f, 0.f);
  if (c < 25) {
    #pragma unroll
    for (int j = 0; j < L_ / 8; ++j) {         // 25 items per thread
      const int idx = row[s + 8 * j];
      if (idx > 0) {
        const float4 v = *(const float4*)&emb[(size_t)(idx - 1) * DIM_ + c * 4];
        acc.x += v.x; acc.y += v.y; acc.z += v.z; acc.w += v.w;
      }
    }
  }
  __shared__ float4 sm[8][32];                 // 4 KB
  sm[s][c] = acc;
  __syncthreads();
  if (s < 4) {
    float4 o = sm[s + 4][c];
    sm[s][c].x += o.x; sm[s][c].y += o.y; sm[s][c].z += o.z; sm[s][c].w += o.w;
  }
  __syncthreads();
  if (s < 2) {
    float4 o = sm[s + 2][c];
    sm[s][c].x += o.x; sm[s][c].y += o.y; sm[s][c].z += o.z; sm[s][c].w += o.w;
  }
  __syncthreads();
  if (s == 0) {
    float4 a0 = sm[0][c], a1 = sm[1][c];
    const float inv = 1.f / slen[b];
    float4 r;
    r.x = (a0.x + a1.x) * inv; r.y = (a0.y + a1.y) * inv;
    r.z = (a0.z + a1.z) * inv; r.w = (a0.w + a1.w) * inv;
    relP4[b * 32 + c] = (c < 25) ? r : make_float4(0.f, 0.f, 0.f, 0.f);
  }
}

// ---------------- Kernel 2/4: split-K GEMM -> private partial chunks --------
// A: [1024][1024] row-major, Bm: [1024][NP], Cpart: [NCH][1024][NP]
// One staging phase per block (whole 128-row K-chunk, 72 KB LDS), one barrier.
__global__ __launch_bounds__(256) void gemm_splitk_k(
    const float* __restrict__ A,
    const float* __restrict__ Bm,
    float* __restrict__ Cpart) {
  __shared__ float As[BM][KCH];   // 16x128 = 8 KB
  __shared__ float Bs[KCH][NP];   // 128x128 = 64 KB
  const int t   = threadIdx.x;
  const int m0  = blockIdx.x * BM;
  const int k0  = blockIdx.y * KCH;
  const int tc  = t & 31;        // col group: cols tc*4 .. tc*4+3
  const int tr  = t >> 5;        // 0..7 : rows tr*2, tr*2+1

  // stage A chunk: 2048 floats = 512 float4, 2 per thread (512B/row coalesced)
  #pragma unroll
  for (int q = 0; q < 2; ++q) {
    const int f = t + q * 256;            // 0..511
    const int r = f >> 5, kk = (f & 31) * 4;
    *(float4*)&As[r][kk] = *(const float4*)&A[(size_t)(m0 + r) * K_ + (k0 + kk)];
  }
  // stage B chunk: 16384 floats = 4096 float4, 16 per thread, coalesced
  #pragma unroll
  for (int q = 0; q < 16; ++q) {
    const int f = t + q * 256;            // 0..4095
    const int r = f >> 5, c = (f & 31) * 4;
    *(float4*)&Bs[r][c] = *(const float4*)&Bm[(size_t)(k0 + r) * NP + c];
  }
  __syncthreads();

  float acc[2][4] = {};
  for (int kk4 = 0; kk4 < KCH; kk4 += 4) {
    float a[2][4], bb[4][4];
    #pragma unroll
    for (int i = 0; i < 2; ++i)      // A frag: 32-lane broadcast (free)
      *(float4*)a[i] = *(const float4*)&As[tr * 2 + i][kk4];
    #pragma unroll
    for (int j = 0; j < 4; ++j)      // B frag: consecutive-lane b128
      *(float4*)bb[j] = *(const float4*)&Bs[kk4 + j][tc * 4];
    #pragma unroll
    for (int j = 0; j < 4; ++j)
      #pragma unroll
      for (int i = 0; i < 2; ++i)
        #pragma unroll
        for (int c = 0; c < 4; ++c)
          acc[i][c] += a[i][j] * bb[j][c];
  }

  float* Cc = Cpart + (size_t)blockIdx.y * B_ * NP;
  #pragma unroll
  for (int i = 0; i < 2; ++i)
    *(float4*)&Cc[(size_t)(m0 + tr * 2 + i) * NP + tc * 4] = *(float4*)acc[i];
}

// ---------------- Kernel 3: reduce 8 partial chunks -> t --------------------
__global__ __launch_bounds__(256) void reduce_k(
    const float* __restrict__ part, float* __restrict__ outm) {
  const int i4 = blockIdx.x * 256 + threadIdx.x;       // float4 index, 32768
  const float4* p = (const float4*)part;
  float4 v = p[i4];
  #pragma unroll
  for (int c = 1; c < NCH; ++c) {
    float4 w = p[(size_t)c * (B_ * NP / 4) + i4];
    v.x += w.x; v.y += w.y; v.z += w.z; v.w += w.w;
  }
  ((float4*)outm)[i4] = v;
}

// ---------------- Kernel 5: sum partials + SELU + row L2-normalize ----------
// 256 thr = 8 rows x 32 f4-lanes; 128 blocks. Padding cols are exactly zero.
__global__ __launch_bounds__(256) void epilogue_k(
    const float* __restrict__ prePart, float* __restrict__ out) {
  const int t  = threadIdx.x;
  const int r  = t >> 5;                 // row within block
  const int c4 = t & 31;                 // f4 col 0..31 (valid out cols: c4<25)
  const int b  = blockIdx.x * 8 + r;
  const float4* p = (const float4*)prePart;
  float4 x = make_float4(0.f, 0.f, 0.f, 0.f);
  #pragma unroll
  for (int q = 0; q < NCH; ++q) {
    float4 w = p[(size_t)q * (B_ * NP / 4) + b * 32 + c4];
    x.x += w.x; x.y += w.y; x.z += w.z; x.w += w.w;
  }
  const float scale = 1.0507009873554804934f;
  const float alpha = 1.6732632423543772848f;
  float4 s;
  s.x = (x.x > 0.f) ? scale * x.x : scale * alpha * expm1f(x.x);
  s.y = (x.y > 0.f) ? scale * x.y : scale * alpha * expm1f(x.y);
  s.z = (x.z > 0.f) ? scale * x.z : scale * alpha * expm1f(x.z);
  s.w = (x.w > 0.f) ? scale * x.w : scale * alpha * expm1f(x.w);
  float ss = s.x * s.x + s.y * s.y + s.z * s.z + s.w * s.w;
  #pragma unroll
  for (int m = 16; m > 0; m >>= 1) ss += __shfl_xor(ss, m, 64);  // 32-lane group
  const float inv = 1.f / sqrtf(ss);
  if (c4 < 25) {
    float4 o; o.x = s.x * inv; o.y = s.y * inv; o.z = s.z * inv; o.w = s.w * inv;
    *(float4*)&out[(size_t)b * DIM_ + c4 * 4] = o;
  }
}

extern "C" void kernel_launch(void* const* d_in, const int* in_sizes, int n_in,
                              void* d_out, int out_size, void* d_ws, size_t ws_size,
                              hipStream_t stream) {
  const float* emb   = (const float*)d_in[0];  // [50000][100]
  const int*   items = (const int*)d_in[1];    // [1024][200]
  const float* A     = (const float*)d_in[2];  // [1024][1024]
  const float* D     = (const float*)d_in[3];  // [1024][1024]
  const float* slen  = (const float*)d_in[4];  // [1024]
  float* out = (float*)d_out;                  // [1024][100]

  char* ws = (char*)d_ws;
  const size_t matB = (size_t)B_ * NP * sizeof(float);   // 512 KB
  float* relP    = (float*)(ws);                          // [1024][128]
  float* tPart   = (float*)(ws + 1 * matB);               // [8][1024][128] = 4 MB
  float* tM      = (float*)(ws + 9 * matB);               // [1024][128]
  float* prePart = (float*)(ws + 10 * matB);              // [8][1024][128] = 4 MB

  // 1. rel = mean-pool(gather)      (float4 gathers, no atomics)
  gather_pool_k<<<B_, 256, 0, stream>>>(emb, items, slen, (float4*)relP);
  // 2. tPart[p] = A_chunk_p @ rel   (reassociated: D@(A@rel), 5x fewer FLOPs)
  gemm_splitk_k<<<dim3(B_ / BM, NCH), 256, 0, stream>>>(A, relP, tPart);
  // 3. t = sum_p tPart[p]
  reduce_k<<<B_ * NP / 4 / 256, 256, 0, stream>>>(tPart, tM);
  // 4. prePart[p] = D_chunk_p @ t
  gemm_splitk_k<<<dim3(B_ / BM, NCH), 256, 0, stream>>>(D, tM, prePart);
  // 5. out = rownorm(selu(sum_p prePart[p]))
  epilogue_k<<<128, 256, 0, stream>>>(prePart, out);
}